// Round 1
// baseline (300.794 us; speedup 1.0000x reference)
//
#include <hip/hip_runtime.h>
#include <math.h>

#define B   16
#define M   1024
#define W   256
#define H   8
#define NW  2
#define NR  4
#define EPSF 1e-6f

// ---------------------------------------------------------------------------
// Generic float4 grid-stride copy (link passthrough, precedence copy)
// ---------------------------------------------------------------------------
__global__ void __launch_bounds__(256) copy4_kernel(float4* __restrict__ dst,
                                                    const float4* __restrict__ src,
                                                    int n4) {
    int i = blockIdx.x * blockDim.x + threadIdx.x;
    int stride = gridDim.x * blockDim.x;
    for (; i < n4; i += stride) dst[i] = src[i];
}

// ---------------------------------------------------------------------------
// Key norms + softplus(strengths) -> ws[0..127]=key_norm, ws[128..255]=sp
// ---------------------------------------------------------------------------
__global__ void prep_kernel(const float* __restrict__ keys,
                            const float* __restrict__ strengths,
                            float* __restrict__ ws) {
    int tid = threadIdx.x;              // 0..127 == b*H + h
    const float4* k = (const float4*)(keys) + (size_t)tid * (W / 4);
    float s = 0.f;
    #pragma unroll 4
    for (int i = 0; i < W / 4; ++i) {
        float4 v = k[i];
        s += v.x * v.x + v.y * v.y + v.z * v.z + v.w * v.w;
    }
    ws[tid] = sqrtf(s + EPSF);
    ws[128 + tid] = log1pf(expf(strengths[tid]));
}

// ---------------------------------------------------------------------------
// One wave (64 lanes) per (b,m) memory row of W=256 floats (float4/lane).
// Fuses: row norm, 8 key dot-products, erase+write update, sharp-score write.
// ---------------------------------------------------------------------------
__global__ void __launch_bounds__(64) memory_kernel(
    const float* __restrict__ memory, const float* __restrict__ keys,
    const float* __restrict__ ww,     const float* __restrict__ ev,
    const float* __restrict__ wv,     const float* __restrict__ ws,
    float* __restrict__ out_mem,      float* __restrict__ out_cos) {
    int bm = blockIdx.x;
    int b = bm >> 10;
    int m = bm & 1023;
    int lane = threadIdx.x;

    float4 x = ((const float4*)memory)[(size_t)bm * (W / 4) + lane];

    float acc[9];
    acc[8] = x.x * x.x + x.y * x.y + x.z * x.z + x.w * x.w;   // norm partial
    const float4* kb = (const float4*)(keys) + (size_t)b * H * (W / 4);
    #pragma unroll
    for (int h = 0; h < H; ++h) {
        float4 k = kb[h * (W / 4) + lane];
        acc[h] = x.x * k.x + x.y * k.y + x.z * k.z + x.w * k.w;
    }
    // butterfly reduce all 9 accumulators across the 64-lane wave
    #pragma unroll
    for (int off = 1; off < 64; off <<= 1) {
        #pragma unroll
        for (int j = 0; j < 9; ++j) acc[j] += __shfl_xor(acc[j], off);
    }
    float mem_norm = sqrtf(acc[8] + EPSF);

    // erase / write update for this row
    float w0 = ww[(b * NW + 0) * M + m];
    float w1 = ww[(b * NW + 1) * M + m];
    const float4* e0p = (const float4*)(ev) + (size_t)(b * NW) * (W / 4);
    const float4* v0p = (const float4*)(wv) + (size_t)(b * NW) * (W / 4);
    float4 e0 = e0p[lane], e1 = e0p[(W / 4) + lane];
    float4 v0 = v0p[lane], v1 = v0p[(W / 4) + lane];
    float4 r;
    {
        float e;
        e = fminf(fmaxf(w0 * e0.x + w1 * e1.x, 0.f), 1.f);
        r.x = x.x * (1.f - e) + w0 * v0.x + w1 * v1.x;
        e = fminf(fmaxf(w0 * e0.y + w1 * e1.y, 0.f), 1.f);
        r.y = x.y * (1.f - e) + w0 * v0.y + w1 * v1.y;
        e = fminf(fmaxf(w0 * e0.z + w1 * e1.z, 0.f), 1.f);
        r.z = x.z * (1.f - e) + w0 * v0.z + w1 * v1.z;
        e = fminf(fmaxf(w0 * e0.w + w1 * e1.w, 0.f), 1.f);
        r.w = x.w * (1.f - e) + w0 * v0.w + w1 * v1.w;
    }
    ((float4*)out_mem)[(size_t)bm * (W / 4) + lane] = r;

    // sharp score: lane h writes head h
    if (lane < H) {
        float d = acc[0];
        #pragma unroll
        for (int h = 1; h < H; ++h)
            if (lane == h) d = acc[h];
        float kn = ws[b * H + lane];
        float sp = ws[128 + b * H + lane];
        out_cos[(size_t)(b * H + lane) * M + m] = d / (mem_norm * kn + EPSF) * sp;
    }
}

// ---------------------------------------------------------------------------
// In-place softmax over M=1024 per (b,h) row. 256 threads, 4 elems/thread.
// ---------------------------------------------------------------------------
__global__ void __launch_bounds__(256) softmax_kernel(float* __restrict__ cosr) {
    int bh = blockIdx.x;
    float* row = cosr + (size_t)bh * M;
    int t = threadIdx.x;
    int wid = t >> 6;

    float v[4];
    #pragma unroll
    for (int c = 0; c < 4; ++c) v[c] = row[t + c * 256];

    float mx = fmaxf(fmaxf(v[0], v[1]), fmaxf(v[2], v[3]));
    #pragma unroll
    for (int off = 1; off < 64; off <<= 1) mx = fmaxf(mx, __shfl_xor(mx, off));
    __shared__ float sm[4];
    if ((t & 63) == 0) sm[wid] = mx;
    __syncthreads();
    mx = fmaxf(fmaxf(sm[0], sm[1]), fmaxf(sm[2], sm[3]));

    float s = 0.f;
    #pragma unroll
    for (int c = 0; c < 4; ++c) { v[c] = expf(v[c] - mx); s += v[c]; }
    #pragma unroll
    for (int off = 1; off < 64; off <<= 1) s += __shfl_xor(s, off);
    __shared__ float ss[4];
    if ((t & 63) == 0) ss[wid] = s;
    __syncthreads();
    float inv = 1.f / (ss[0] + ss[1] + ss[2] + ss[3]);

    #pragma unroll
    for (int c = 0; c < 4; ++c) row[t + c * 256] = v[c] * inv;
}

// ---------------------------------------------------------------------------
// Usage update + read_output. One block per batch.
// ---------------------------------------------------------------------------
__global__ void __launch_bounds__(256) misc_kernel(
    const float* __restrict__ ww, const float* __restrict__ fg,
    const float* __restrict__ rw, const float* __restrict__ pu,
    const float* __restrict__ rv,
    float* __restrict__ out_usage, float* __restrict__ out_read) {
    int b = blockIdx.x, t = threadIdx.x;
    int wid = t >> 6;

    float f[NR];
    #pragma unroll
    for (int n = 0; n < NR; ++n) f[n] = fg[b * NR + n];

    float part[NR] = {0.f, 0.f, 0.f, 0.f};
    #pragma unroll
    for (int c = 0; c < 4; ++c) {
        int m = t + c * 256;
        float u = pu[b * M + m] + ww[(b * NW + 0) * M + m] + ww[(b * NW + 1) * M + m];
        #pragma unroll
        for (int n = 0; n < NR; ++n) {
            float r = rw[(size_t)(b * NR + n) * M + m];
            part[n] += r;
            u -= r * f[n];
        }
        out_usage[b * M + m] = fminf(fmaxf(u, 0.f), 1.f);
    }

    #pragma unroll
    for (int off = 1; off < 64; off <<= 1) {
        #pragma unroll
        for (int n = 0; n < NR; ++n) part[n] += __shfl_xor(part[n], off);
    }
    __shared__ float sp[4][NR];
    if ((t & 63) == 0) {
        #pragma unroll
        for (int n = 0; n < NR; ++n) sp[wid][n] = part[n];
    }
    __syncthreads();

    float ro = 0.f;
    #pragma unroll
    for (int n = 0; n < NR; ++n) {
        float rs = sp[0][n] + sp[1][n] + sp[2][n] + sp[3][n];
        ro += rs * rv[(size_t)(b * NR + n) * W + t];
    }
    out_read[b * W + t] = ro;
}

// ---------------------------------------------------------------------------
extern "C" void kernel_launch(void* const* d_in, const int* in_sizes, int n_in,
                              void* d_out, int out_size, void* d_ws, size_t ws_size,
                              hipStream_t stream) {
    const float* memory        = (const float*)d_in[0];
    const float* keys          = (const float*)d_in[1];
    const float* strengths     = (const float*)d_in[2];
    const float* write_weights = (const float*)d_in[3];
    const float* free_gate     = (const float*)d_in[4];
    const float* read_weights  = (const float*)d_in[5];
    const float* prev_link     = (const float*)d_in[6];
    // d_in[7] prev_precedence_weights: unused (precedence := write_weights)
    const float* prev_usage    = (const float*)d_in[8];
    const float* erase_vectors = (const float*)d_in[9];
    const float* write_vectors = (const float*)d_in[10];
    const float* read_vectors  = (const float*)d_in[11];

    float* out = (float*)d_out;
    // output layout (flat concat, fp32):
    float* out_mem   = out;                       // [B,M,W]     4,194,304
    float* out_cos   = out + 4194304;             // [B,H,M]       131,072
    float* out_link  = out + 4325376;             // [B,NW,M,M] 33,554,432
    float* out_prec  = out + 37879808;            // [B,NW,M]       32,768
    float* out_usage = out + 37912576;            // [B,M]          16,384
    float* out_read  = out + 37928960;            // [B,W]           4,096

    float* ws = (float*)d_ws;                     // 256 floats used

    hipLaunchKernelGGL(prep_kernel, dim3(1), dim3(B * H), 0, stream,
                       keys, strengths, ws);
    hipLaunchKernelGGL(memory_kernel, dim3(B * M), dim3(64), 0, stream,
                       memory, keys, write_weights, erase_vectors,
                       write_vectors, ws, out_mem, out_cos);
    hipLaunchKernelGGL(softmax_kernel, dim3(B * H), dim3(256), 0, stream,
                       out_cos);
    hipLaunchKernelGGL(misc_kernel, dim3(B), dim3(256), 0, stream,
                       write_weights, free_gate, read_weights, prev_usage,
                       read_vectors, out_usage, out_read);
    // link passthrough: 33,554,432 floats = 8,388,608 float4
    hipLaunchKernelGGL(copy4_kernel, dim3(8192), dim3(256), 0, stream,
                       (float4*)out_link, (const float4*)prev_link, 8388608);
    // precedence := write_weights: 32,768 floats = 8,192 float4
    hipLaunchKernelGGL(copy4_kernel, dim3(32), dim3(256), 0, stream,
                       (float4*)out_prec, (const float4*)write_weights, 8192);
}

// Round 3
// 274.226 us; speedup vs baseline: 1.0969x; 1.0969x over previous
//
#include <hip/hip_runtime.h>
#include <math.h>

#define B   16
#define M   1024
#define W   256
#define H   8
#define NW  2
#define NR  4
#define EPSF 1e-6f

// clang native vector type — accepted by __builtin_nontemporal_*
typedef float v4f __attribute__((ext_vector_type(4)));

// Block-range partition of the mega kernel:
//   [0, 4096)        : link copy (8,388,608 v4f, 2048 per block, nontemporal)
//   [4096, 8192)     : memory rows (4 waves/block, 1 wave per (b,m) row)
//   [8192, 8208)     : misc (usage + read_output), 1 block per batch
//   [8208, 8240)     : precedence copy (8192 v4f)
#define NBLK_COPY 4096
#define NBLK_MEM  4096
#define NBLK_MISC 16
#define NBLK_PREC 32

__global__ void __launch_bounds__(256) mega_kernel(
    const float* __restrict__ memory, const float* __restrict__ keys,
    const float* __restrict__ ww,     const float* __restrict__ fg,
    const float* __restrict__ rw,     const float* __restrict__ prev_link,
    const float* __restrict__ pu,     const float* __restrict__ ev,
    const float* __restrict__ wv,     const float* __restrict__ rv,
    float* __restrict__ out_mem,      float* __restrict__ out_cos,
    float* __restrict__ out_link,     float* __restrict__ out_prec,
    float* __restrict__ out_usage,    float* __restrict__ out_read,
    float* __restrict__ ws_norm) {
    int blk = blockIdx.x;
    int t = threadIdx.x;

    if (blk < NBLK_COPY) {
        // ------------------ link passthrough copy (268 MB of traffic) -----
        const v4f* s4 = (const v4f*)prev_link;
        v4f* d4 = (v4f*)out_link;
        int base = blk * 2048 + t;
        v4f val[8];
        #pragma unroll
        for (int u = 0; u < 8; ++u)
            val[u] = __builtin_nontemporal_load(&s4[base + u * 256]);
        #pragma unroll
        for (int u = 0; u < 8; ++u)
            __builtin_nontemporal_store(val[u], &d4[base + u * 256]);
        return;
    }

    if (blk < NBLK_COPY + NBLK_MEM) {
        // ------------------ memory row update + raw key dots --------------
        int lane = t & 63;
        int wid = t >> 6;
        int bm = (blk - NBLK_COPY) * 4 + wid;      // [0, 16384)
        int b = bm >> 10;
        int m = bm & 1023;

        v4f x = __builtin_nontemporal_load(
            ((const v4f*)memory) + (size_t)bm * (W / 4) + lane);

        float acc[9];
        acc[8] = x.x * x.x + x.y * x.y + x.z * x.z + x.w * x.w;
        const v4f* kb = (const v4f*)(keys) + (size_t)b * H * (W / 4);
        #pragma unroll
        for (int h = 0; h < H; ++h) {
            v4f k = kb[h * (W / 4) + lane];
            acc[h] = x.x * k.x + x.y * k.y + x.z * k.z + x.w * k.w;
        }
        #pragma unroll
        for (int off = 1; off < 64; off <<= 1) {
            #pragma unroll
            for (int j = 0; j < 9; ++j) acc[j] += __shfl_xor(acc[j], off);
        }

        // erase / write update
        float w0 = ww[(b * NW + 0) * M + m];
        float w1 = ww[(b * NW + 1) * M + m];
        const v4f* e0p = (const v4f*)(ev) + (size_t)(b * NW) * (W / 4);
        const v4f* v0p = (const v4f*)(wv) + (size_t)(b * NW) * (W / 4);
        v4f e0 = e0p[lane], e1 = e0p[(W / 4) + lane];
        v4f v0 = v0p[lane], v1 = v0p[(W / 4) + lane];
        v4f r;
        {
            float e;
            e = fminf(fmaxf(w0 * e0.x + w1 * e1.x, 0.f), 1.f);
            r.x = x.x * (1.f - e) + w0 * v0.x + w1 * v1.x;
            e = fminf(fmaxf(w0 * e0.y + w1 * e1.y, 0.f), 1.f);
            r.y = x.y * (1.f - e) + w0 * v0.y + w1 * v1.y;
            e = fminf(fmaxf(w0 * e0.z + w1 * e1.z, 0.f), 1.f);
            r.z = x.z * (1.f - e) + w0 * v0.z + w1 * v1.z;
            e = fminf(fmaxf(w0 * e0.w + w1 * e1.w, 0.f), 1.f);
            r.w = x.w * (1.f - e) + w0 * v0.w + w1 * v1.w;
        }
        __builtin_nontemporal_store(r,
            ((v4f*)out_mem) + (size_t)bm * (W / 4) + lane);

        // raw dot per head (cosine scale deferred to softmax kernel)
        if (lane < H) {
            float d = acc[0];
            #pragma unroll
            for (int h = 1; h < H; ++h)
                if (lane == h) d = acc[h];
            out_cos[(size_t)(b * H + lane) * M + m] = d;
        }
        if (lane == 0) ws_norm[bm] = sqrtf(acc[8] + EPSF);
        return;
    }

    if (blk < NBLK_COPY + NBLK_MEM + NBLK_MISC) {
        // ------------------ usage + read_output ---------------------------
        int b = blk - (NBLK_COPY + NBLK_MEM);
        int wid = t >> 6;
        __shared__ float sp[4][NR];

        float f[NR];
        #pragma unroll
        for (int n = 0; n < NR; ++n) f[n] = fg[b * NR + n];

        float part[NR] = {0.f, 0.f, 0.f, 0.f};
        #pragma unroll
        for (int c = 0; c < 4; ++c) {
            int m = t + c * 256;
            float u = pu[b * M + m] + ww[(b * NW + 0) * M + m]
                                    + ww[(b * NW + 1) * M + m];
            #pragma unroll
            for (int n = 0; n < NR; ++n) {
                float r = rw[(size_t)(b * NR + n) * M + m];
                part[n] += r;
                u -= r * f[n];
            }
            out_usage[b * M + m] = fminf(fmaxf(u, 0.f), 1.f);
        }

        #pragma unroll
        for (int off = 1; off < 64; off <<= 1) {
            #pragma unroll
            for (int n = 0; n < NR; ++n) part[n] += __shfl_xor(part[n], off);
        }
        if ((t & 63) == 0) {
            #pragma unroll
            for (int n = 0; n < NR; ++n) sp[wid][n] = part[n];
        }
        __syncthreads();

        float ro = 0.f;
        #pragma unroll
        for (int n = 0; n < NR; ++n) {
            float rs = sp[0][n] + sp[1][n] + sp[2][n] + sp[3][n];
            ro += rs * rv[(size_t)(b * NR + n) * W + t];
        }
        out_read[b * W + t] = ro;
        return;
    }

    // ---------------------- precedence := write_weights -------------------
    {
        int i = (blk - (NBLK_COPY + NBLK_MEM + NBLK_MISC)) * 256 + t; // [0,8192)
        ((v4f*)out_prec)[i] = ((const v4f*)ww)[i];
    }
}

// ---------------------------------------------------------------------------
// Softmax + cosine scaling. One block per (b,h). Computes key norm and
// softplus(strength) locally; reads raw dots + mem_norms from mega kernel.
// ---------------------------------------------------------------------------
__global__ void __launch_bounds__(256) softmax_kernel(
    const float* __restrict__ keys, const float* __restrict__ strengths,
    const float* __restrict__ ws_norm, float* __restrict__ cosr) {
    int bh = blockIdx.x;
    int b = bh >> 3;
    int t = threadIdx.x;
    int wid = t >> 6;
    __shared__ float skn[4];
    __shared__ float sm[4];
    __shared__ float ss[4];

    // key L2 norm (256 elems, 1/thread)
    float kv = keys[(size_t)bh * W + t];
    float s = kv * kv;
    #pragma unroll
    for (int off = 1; off < 64; off <<= 1) s += __shfl_xor(s, off);
    if ((t & 63) == 0) skn[wid] = s;
    __syncthreads();
    float kn = sqrtf(skn[0] + skn[1] + skn[2] + skn[3] + EPSF);
    float sp = log1pf(expf(strengths[bh]));

    float* row = cosr + (size_t)bh * M;
    float v[4];
    #pragma unroll
    for (int c = 0; c < 4; ++c) {
        int m = t + c * 256;
        float d = row[m];
        float nm = ws_norm[b * M + m];
        v[c] = d / (nm * kn + EPSF) * sp;
    }

    float mx = fmaxf(fmaxf(v[0], v[1]), fmaxf(v[2], v[3]));
    #pragma unroll
    for (int off = 1; off < 64; off <<= 1) mx = fmaxf(mx, __shfl_xor(mx, off));
    if ((t & 63) == 0) sm[wid] = mx;
    __syncthreads();
    mx = fmaxf(fmaxf(sm[0], sm[1]), fmaxf(sm[2], sm[3]));

    float sum = 0.f;
    #pragma unroll
    for (int c = 0; c < 4; ++c) { v[c] = expf(v[c] - mx); sum += v[c]; }
    #pragma unroll
    for (int off = 1; off < 64; off <<= 1) sum += __shfl_xor(sum, off);
    if ((t & 63) == 0) ss[wid] = sum;
    __syncthreads();
    float inv = 1.f / (ss[0] + ss[1] + ss[2] + ss[3]);

    #pragma unroll
    for (int c = 0; c < 4; ++c) row[t + c * 256] = v[c] * inv;
}

// ---------------------------------------------------------------------------
extern "C" void kernel_launch(void* const* d_in, const int* in_sizes, int n_in,
                              void* d_out, int out_size, void* d_ws, size_t ws_size,
                              hipStream_t stream) {
    const float* memory        = (const float*)d_in[0];
    const float* keys          = (const float*)d_in[1];
    const float* strengths     = (const float*)d_in[2];
    const float* write_weights = (const float*)d_in[3];
    const float* free_gate     = (const float*)d_in[4];
    const float* read_weights  = (const float*)d_in[5];
    const float* prev_link     = (const float*)d_in[6];
    const float* prev_usage    = (const float*)d_in[8];
    const float* erase_vectors = (const float*)d_in[9];
    const float* write_vectors = (const float*)d_in[10];
    const float* read_vectors  = (const float*)d_in[11];

    float* out = (float*)d_out;
    float* out_mem   = out;                       // [B,M,W]     4,194,304
    float* out_cos   = out + 4194304;             // [B,H,M]       131,072
    float* out_link  = out + 4325376;             // [B,NW,M,M] 33,554,432
    float* out_prec  = out + 37879808;            // [B,NW,M]       32,768
    float* out_usage = out + 37912576;            // [B,M]          16,384
    float* out_read  = out + 37928960;            // [B,W]           4,096

    float* ws_norm = (float*)d_ws;                // [B*M] = 16,384 floats

    hipLaunchKernelGGL(mega_kernel,
                       dim3(NBLK_COPY + NBLK_MEM + NBLK_MISC + NBLK_PREC),
                       dim3(256), 0, stream,
                       memory, keys, write_weights, free_gate, read_weights,
                       prev_link, prev_usage, erase_vectors, write_vectors,
                       read_vectors,
                       out_mem, out_cos, out_link, out_prec, out_usage,
                       out_read, ws_norm);
    hipLaunchKernelGGL(softmax_kernel, dim3(B * H), dim3(256), 0, stream,
                       keys, strengths, ws_norm, out_cos);
}

// Round 4
// 272.949 us; speedup vs baseline: 1.1020x; 1.0047x over previous
//
#include <hip/hip_runtime.h>
#include <math.h>

#define B   16
#define M   1024
#define W   256
#define H   8
#define NW  2
#define NR  4
#define EPSF 1e-6f

// clang native vector type — accepted by __builtin_nontemporal_*
typedef float v4f __attribute__((ext_vector_type(4)));

// Kernel 1: 4096 UNIFORM blocks. Each block:
//   - 4 waves, one (b,m) memory row each (norm + 8 key dots + erase/write)
//   - a 2048-float4 (32 KB) slice of the link copy, interleaved so copy-load
//     latency hides under the dot-product VALU work.
#define NBLK_MEGA 4096

__global__ void __launch_bounds__(256) mega_kernel(
    const float* __restrict__ memory, const float* __restrict__ keys,
    const float* __restrict__ ww,     const float* __restrict__ prev_link,
    const float* __restrict__ ev,     const float* __restrict__ wv,
    float* __restrict__ out_mem,      float* __restrict__ out_cos,
    float* __restrict__ out_link,     float* __restrict__ ws_norm) {
    int blk = blockIdx.x;
    int t = threadIdx.x;
    int lane = t & 63;
    int wid = t >> 6;
    int bm = blk * 4 + wid;                        // [0, 16384)
    int b = bm >> 10;
    int m = bm & 1023;

    const v4f* s4 = (const v4f*)prev_link;
    v4f* d4 = (v4f*)out_link;
    int cbase = blk * 2048 + t;

    // ---- copy first half: issue loads, keep in flight --------------------
    v4f cv[4];
    #pragma unroll
    for (int u = 0; u < 4; ++u)
        cv[u] = __builtin_nontemporal_load(&s4[cbase + u * 256]);

    // ---- memory row: load + norm + key dots (hides copy-load latency) ----
    v4f x = __builtin_nontemporal_load(
        ((const v4f*)memory) + (size_t)bm * (W / 4) + lane);

    float acc[9];
    acc[8] = x.x * x.x + x.y * x.y + x.z * x.z + x.w * x.w;
    const v4f* kb = (const v4f*)(keys) + (size_t)b * H * (W / 4);
    #pragma unroll
    for (int h = 0; h < H; ++h) {
        v4f k = kb[h * (W / 4) + lane];
        acc[h] = x.x * k.x + x.y * k.y + x.z * k.z + x.w * k.w;
    }
    #pragma unroll
    for (int off = 1; off < 64; off <<= 1) {
        #pragma unroll
        for (int j = 0; j < 9; ++j) acc[j] += __shfl_xor(acc[j], off);
    }

    // ---- drain copy first half, launch second half -----------------------
    #pragma unroll
    for (int u = 0; u < 4; ++u)
        __builtin_nontemporal_store(cv[u], &d4[cbase + u * 256]);
    #pragma unroll
    for (int u = 0; u < 4; ++u)
        cv[u] = __builtin_nontemporal_load(&s4[cbase + (u + 4) * 256]);

    // ---- erase / write update (hides second copy-load latency) -----------
    float w0 = ww[(b * NW + 0) * M + m];
    float w1 = ww[(b * NW + 1) * M + m];
    const v4f* e0p = (const v4f*)(ev) + (size_t)(b * NW) * (W / 4);
    const v4f* v0p = (const v4f*)(wv) + (size_t)(b * NW) * (W / 4);
    v4f e0 = e0p[lane], e1 = e0p[(W / 4) + lane];
    v4f v0 = v0p[lane], v1 = v0p[(W / 4) + lane];
    v4f r;
    {
        float e;
        e = fminf(fmaxf(w0 * e0.x + w1 * e1.x, 0.f), 1.f);
        r.x = x.x * (1.f - e) + w0 * v0.x + w1 * v1.x;
        e = fminf(fmaxf(w0 * e0.y + w1 * e1.y, 0.f), 1.f);
        r.y = x.y * (1.f - e) + w0 * v0.y + w1 * v1.y;
        e = fminf(fmaxf(w0 * e0.z + w1 * e1.z, 0.f), 1.f);
        r.z = x.z * (1.f - e) + w0 * v0.z + w1 * v1.z;
        e = fminf(fmaxf(w0 * e0.w + w1 * e1.w, 0.f), 1.f);
        r.w = x.w * (1.f - e) + w0 * v0.w + w1 * v1.w;
    }
    __builtin_nontemporal_store(r,
        ((v4f*)out_mem) + (size_t)bm * (W / 4) + lane);

    // raw dot per head (cosine scale deferred to kernel 2)
    if (lane < H) {
        float d = acc[0];
        #pragma unroll
        for (int h = 1; h < H; ++h)
            if (lane == h) d = acc[h];
        out_cos[(size_t)(b * H + lane) * M + m] = d;
    }
    if (lane == 0) ws_norm[bm] = sqrtf(acc[8] + EPSF);

    // ---- drain copy second half ------------------------------------------
    #pragma unroll
    for (int u = 0; u < 4; ++u)
        __builtin_nontemporal_store(cv[u], &d4[cbase + (u + 4) * 256]);
}

// ---------------------------------------------------------------------------
// Kernel 2: [0,128) softmax+cosine per (b,h) | [128,144) misc | [144,176) prec
// ---------------------------------------------------------------------------
__global__ void __launch_bounds__(256) finish_kernel(
    const float* __restrict__ keys, const float* __restrict__ strengths,
    const float* __restrict__ ws_norm, const float* __restrict__ ww,
    const float* __restrict__ fg,   const float* __restrict__ rw,
    const float* __restrict__ pu,   const float* __restrict__ rv,
    float* __restrict__ cosr,       float* __restrict__ out_prec,
    float* __restrict__ out_usage,  float* __restrict__ out_read) {
    int blk = blockIdx.x;
    int t = threadIdx.x;
    int wid = t >> 6;

    if (blk < B * H) {
        // ------------------ softmax + cosine scaling ----------------------
        int bh = blk;
        int b = bh >> 3;
        __shared__ float skn[4];
        __shared__ float sm[4];
        __shared__ float ss[4];

        float kv = keys[(size_t)bh * W + t];
        float s = kv * kv;
        #pragma unroll
        for (int off = 1; off < 64; off <<= 1) s += __shfl_xor(s, off);
        if ((t & 63) == 0) skn[wid] = s;
        __syncthreads();
        float kn = sqrtf(skn[0] + skn[1] + skn[2] + skn[3] + EPSF);
        float sp = log1pf(expf(strengths[bh]));

        float* row = cosr + (size_t)bh * M;
        float v[4];
        #pragma unroll
        for (int c = 0; c < 4; ++c) {
            int m = t + c * 256;
            float d = row[m];
            float nm = ws_norm[b * M + m];
            v[c] = d / (nm * kn + EPSF) * sp;
        }

        float mx = fmaxf(fmaxf(v[0], v[1]), fmaxf(v[2], v[3]));
        #pragma unroll
        for (int off = 1; off < 64; off <<= 1) mx = fmaxf(mx, __shfl_xor(mx, off));
        if ((t & 63) == 0) sm[wid] = mx;
        __syncthreads();
        mx = fmaxf(fmaxf(sm[0], sm[1]), fmaxf(sm[2], sm[3]));

        float sum = 0.f;
        #pragma unroll
        for (int c = 0; c < 4; ++c) { v[c] = expf(v[c] - mx); sum += v[c]; }
        #pragma unroll
        for (int off = 1; off < 64; off <<= 1) sum += __shfl_xor(sum, off);
        if ((t & 63) == 0) ss[wid] = sum;
        __syncthreads();
        float inv = 1.f / (ss[0] + ss[1] + ss[2] + ss[3]);

        #pragma unroll
        for (int c = 0; c < 4; ++c) row[t + c * 256] = v[c] * inv;
        return;
    }

    if (blk < B * H + B) {
        // ------------------ usage + read_output ---------------------------
        int b = blk - B * H;
        __shared__ float spm[4][NR];

        float f[NR];
        #pragma unroll
        for (int n = 0; n < NR; ++n) f[n] = fg[b * NR + n];

        float part[NR] = {0.f, 0.f, 0.f, 0.f};
        #pragma unroll
        for (int c = 0; c < 4; ++c) {
            int m = t + c * 256;
            float u = pu[b * M + m] + ww[(b * NW + 0) * M + m]
                                    + ww[(b * NW + 1) * M + m];
            #pragma unroll
            for (int n = 0; n < NR; ++n) {
                float r = rw[(size_t)(b * NR + n) * M + m];
                part[n] += r;
                u -= r * f[n];
            }
            out_usage[b * M + m] = fminf(fmaxf(u, 0.f), 1.f);
        }

        #pragma unroll
        for (int off = 1; off < 64; off <<= 1) {
            #pragma unroll
            for (int n = 0; n < NR; ++n) part[n] += __shfl_xor(part[n], off);
        }
        if ((t & 63) == 0) {
            #pragma unroll
            for (int n = 0; n < NR; ++n) spm[wid][n] = part[n];
        }
        __syncthreads();

        float ro = 0.f;
        #pragma unroll
        for (int n = 0; n < NR; ++n) {
            float rs = spm[0][n] + spm[1][n] + spm[2][n] + spm[3][n];
            ro += rs * rv[(size_t)(b * NR + n) * W + t];
        }
        out_read[b * W + t] = ro;
        return;
    }

    // ---------------------- precedence := write_weights -------------------
    {
        int i = (blk - (B * H + B)) * 256 + t;     // [0, 8192)
        ((v4f*)out_prec)[i] = ((const v4f*)ww)[i];
    }
}

// ---------------------------------------------------------------------------
extern "C" void kernel_launch(void* const* d_in, const int* in_sizes, int n_in,
                              void* d_out, int out_size, void* d_ws, size_t ws_size,
                              hipStream_t stream) {
    const float* memory        = (const float*)d_in[0];
    const float* keys          = (const float*)d_in[1];
    const float* strengths     = (const float*)d_in[2];
    const float* write_weights = (const float*)d_in[3];
    const float* free_gate     = (const float*)d_in[4];
    const float* read_weights  = (const float*)d_in[5];
    const float* prev_link     = (const float*)d_in[6];
    const float* prev_usage    = (const float*)d_in[8];
    const float* erase_vectors = (const float*)d_in[9];
    const float* write_vectors = (const float*)d_in[10];
    const float* read_vectors  = (const float*)d_in[11];

    float* out = (float*)d_out;
    float* out_mem   = out;                       // [B,M,W]     4,194,304
    float* out_cos   = out + 4194304;             // [B,H,M]       131,072
    float* out_link  = out + 4325376;             // [B,NW,M,M] 33,554,432
    float* out_prec  = out + 37879808;            // [B,NW,M]       32,768
    float* out_usage = out + 37912576;            // [B,M]          16,384
    float* out_read  = out + 37928960;            // [B,W]           4,096

    float* ws_norm = (float*)d_ws;                // [B*M] = 16,384 floats

    hipLaunchKernelGGL(mega_kernel, dim3(NBLK_MEGA), dim3(256), 0, stream,
                       memory, keys, write_weights, prev_link,
                       erase_vectors, write_vectors,
                       out_mem, out_cos, out_link, ws_norm);
    hipLaunchKernelGGL(finish_kernel, dim3(B * H + B + 32), dim3(256), 0,
                       stream,
                       keys, strengths, ws_norm, write_weights, free_gate,
                       read_weights, prev_usage, read_vectors,
                       out_cos, out_prec, out_usage, out_read);
}